// Round 1
// baseline (317.054 us; speedup 1.0000x reference)
//
#include <hip/hip_runtime.h>

#define D_DIM 256
#define K_CODES 1024
#define N_ROWS (32 * 1024)
#define BLOCK_ROWS 64
#define KT 64
#define DC 64
#define LDS_STRIDE 68   // 64 + 4 pad: keeps 16B alignment per row, spreads banks
#define NMAIN (N_ROWS / BLOCK_ROWS)   // 512 blocks

// ---------------------------------------------------------------- kernel 0
// e_norm2[k] = sum_d E[k][d]^2   (one wave per codebook row)
__global__ __launch_bounds__(256) void vq_enorm(const float* __restrict__ E,
                                                float* __restrict__ enorm) {
    int wave = threadIdx.x >> 6;
    int lane = threadIdx.x & 63;
    int k = blockIdx.x * 4 + wave;               // grid = 256 blocks -> k in [0,1024)
    const float4 v = *reinterpret_cast<const float4*>(E + k * D_DIM + lane * 4);
    float s = v.x * v.x + v.y * v.y + v.z * v.z + v.w * v.w;
    #pragma unroll
    for (int off = 32; off; off >>= 1) s += __shfl_xor(s, off, 64);
    if (lane == 0) enorm[k] = s;
}

// ---------------------------------------------------------------- kernel 1
// Per block: 64 rows. Loop 16 k-tiles of 64 codes; full D accumulation per
// tile; running argmin in registers; fused gather-writeback + loss partial.
__global__ __launch_bounds__(256) void vq_main(const float* __restrict__ X,
                                               const float* __restrict__ E,
                                               const float* __restrict__ enorm,
                                               float* __restrict__ outq,
                                               float* __restrict__ loss_partial) {
    __shared__ float Xs[DC][LDS_STRIDE];   // transposed: Xs[d][row]
    __shared__ float Es[DC][LDS_STRIDE];   // transposed: Es[d][code]
    __shared__ float wsum[4];

    const int tid = threadIdx.x;
    const int tx = tid & 15;    // code group (4 codes)
    const int ty = tid >> 4;    // row group  (4 rows)
    const int row0 = blockIdx.x * BLOCK_ROWS;

    float minv[4];
    int   mini[4];
    #pragma unroll
    for (int i = 0; i < 4; ++i) { minv[i] = INFINITY; mini[i] = 0; }

    for (int kt = 0; kt < K_CODES; kt += KT) {
        float acc[4][4] = {};

        for (int dc = 0; dc < D_DIM; dc += DC) {
            __syncthreads();   // protect LDS from previous chunk's readers
            // stage X chunk (64 rows x 64 d), transposed into LDS
            #pragma unroll
            for (int it = 0; it < 4; ++it) {
                int l = tid + it * 256;            // 1024 float4 slots
                int r = l >> 4;
                int dseg = l & 15;
                float4 v = *reinterpret_cast<const float4*>(
                    X + (size_t)(row0 + r) * D_DIM + dc + dseg * 4);
                Xs[dseg * 4 + 0][r] = v.x;
                Xs[dseg * 4 + 1][r] = v.y;
                Xs[dseg * 4 + 2][r] = v.z;
                Xs[dseg * 4 + 3][r] = v.w;
            }
            // stage E chunk (64 codes x 64 d), transposed into LDS
            #pragma unroll
            for (int it = 0; it < 4; ++it) {
                int l = tid + it * 256;
                int r = l >> 4;
                int dseg = l & 15;
                float4 v = *reinterpret_cast<const float4*>(
                    E + (size_t)(kt + r) * D_DIM + dc + dseg * 4);
                Es[dseg * 4 + 0][r] = v.x;
                Es[dseg * 4 + 1][r] = v.y;
                Es[dseg * 4 + 2][r] = v.z;
                Es[dseg * 4 + 3][r] = v.w;
            }
            __syncthreads();

            #pragma unroll
            for (int d = 0; d < DC; ++d) {
                const float4 xv = *reinterpret_cast<const float4*>(&Xs[d][ty << 2]);
                const float4 ev = *reinterpret_cast<const float4*>(&Es[d][tx << 2]);
                const float ax[4] = {xv.x, xv.y, xv.z, xv.w};
                const float ae[4] = {ev.x, ev.y, ev.z, ev.w};
                #pragma unroll
                for (int i = 0; i < 4; ++i)
                    #pragma unroll
                    for (int j = 0; j < 4; ++j)
                        acc[i][j] = fmaf(ax[i], ae[j], acc[i][j]);
            }
        }

        // scores + running-min update (ascending k => strict < keeps first min)
        #pragma unroll
        for (int j = 0; j < 4; ++j) {
            int kk = kt + (tx << 2) + j;
            float en = enorm[kk];
            #pragma unroll
            for (int i = 0; i < 4; ++i) {
                float score = fmaf(-2.0f, acc[i][j], en);
                if (score < minv[i]) { minv[i] = score; mini[i] = kk; }
            }
        }
    }

    // reduce (minv, mini) across the 16 code-lanes sharing the same rows
    #pragma unroll
    for (int off = 8; off >= 1; off >>= 1) {
        #pragma unroll
        for (int i = 0; i < 4; ++i) {
            float ov = __shfl_xor(minv[i], off, 64);
            int   oi = __shfl_xor(mini[i], off, 64);
            if (ov < minv[i] || (ov == minv[i] && oi < mini[i])) {
                minv[i] = ov; mini[i] = oi;
            }
        }
    }

    // gather-writeback + loss accumulation (16 lanes cooperate per row)
    float lsum = 0.0f;
    #pragma unroll
    for (int i = 0; i < 4; ++i) {
        int row = row0 + (ty << 2) + i;
        int idx = mini[i];
        const float* eq = E + (size_t)idx * D_DIM;
        const float* xr = X + (size_t)row * D_DIM;
        float* orow = outq + (size_t)row * D_DIM;
        #pragma unroll
        for (int j = 0; j < 4; ++j) {
            int d = (tx << 2) + (j << 6);   // tx*4 + j*64
            float4 q = *reinterpret_cast<const float4*>(eq + d);
            float4 x = *reinterpret_cast<const float4*>(xr + d);
            *reinterpret_cast<float4*>(orow + d) = q;
            float dx = q.x - x.x, dy = q.y - x.y, dz = q.z - x.z, dw = q.w - x.w;
            lsum += dx * dx + dy * dy + dz * dz + dw * dw;
        }
    }
    #pragma unroll
    for (int off = 32; off; off >>= 1) lsum += __shfl_xor(lsum, off, 64);
    int wave = tid >> 6, lane = tid & 63;
    if (lane == 0) wsum[wave] = lsum;
    __syncthreads();
    if (tid == 0)
        loss_partial[blockIdx.x] = wsum[0] + wsum[1] + wsum[2] + wsum[3];
}

// ---------------------------------------------------------------- kernel 2
// deterministic fold of 512 block partials -> vq_loss scalar
__global__ __launch_bounds__(256) void vq_finalize(const float* __restrict__ partials,
                                                   float* __restrict__ out_loss) {
    __shared__ float s[256];
    int t = threadIdx.x;
    s[t] = partials[t] + partials[t + 256];
    __syncthreads();
    #pragma unroll
    for (int off = 128; off; off >>= 1) {
        if (t < off) s[t] += s[t + off];
        __syncthreads();
    }
    if (t == 0)
        out_loss[0] = s[0] * (1.25f / (float)(N_ROWS * D_DIM));
}

// ---------------------------------------------------------------- launch
extern "C" void kernel_launch(void* const* d_in, const int* in_sizes, int n_in,
                              void* d_out, int out_size, void* d_ws, size_t ws_size,
                              hipStream_t stream) {
    const float* X = (const float*)d_in[0];   // latents  [32768, 256]
    const float* E = (const float*)d_in[1];   // codebook [1024, 256]
    float* out = (float*)d_out;               // [8388608 quantized] + [1 loss]

    float* enorm    = (float*)d_ws;           // 1024 floats
    float* partials = enorm + K_CODES;        // 512 floats

    vq_enorm<<<K_CODES / 4, 256, 0, stream>>>(E, enorm);
    vq_main<<<NMAIN, 256, 0, stream>>>(X, E, enorm, out, partials);
    vq_finalize<<<1, 256, 0, stream>>>(partials, out + (size_t)N_ROWS * D_DIM);
}

// Round 2
// 59.858 us; speedup vs baseline: 5.2968x; 5.2968x over previous
//
#include <hip/hip_runtime.h>
#include <hip/hip_bf16.h>

#define D_DIM 256
#define K_CODES 1024
#define N_ROWS (32 * 1024)
#define BLOCK_ROWS 32            // rows per block (shared by 4 K-split waves)
#define NBLK (N_ROWS / BLOCK_ROWS)   // 1024 main blocks

typedef __attribute__((ext_vector_type(8))) short bf16x8;
typedef __attribute__((ext_vector_type(4))) float f32x4;

static __device__ __forceinline__ short f2bf(float f) {
    __hip_bfloat16 h = __float2bfloat16(f);   // RNE
    return *reinterpret_cast<short*>(&h);
}

static __device__ __forceinline__ bf16x8 pack8(float4 a, float4 b) {
    bf16x8 r;
    r[0] = f2bf(a.x); r[1] = f2bf(a.y); r[2] = f2bf(a.z); r[3] = f2bf(a.w);
    r[4] = f2bf(b.x); r[5] = f2bf(b.y); r[6] = f2bf(b.z); r[7] = f2bf(b.w);
    return r;
}

// ---------------------------------------------------------------- kernel 0
// e_norm2[k] = sum_d E[k][d]^2   (one wave per codebook row, f32)
__global__ __launch_bounds__(256) void vq_enorm(const float* __restrict__ E,
                                                float* __restrict__ enorm) {
    int wave = threadIdx.x >> 6;
    int lane = threadIdx.x & 63;
    int k = blockIdx.x * 4 + wave;               // 256 blocks -> k in [0,1024)
    const float4 v = *reinterpret_cast<const float4*>(E + k * D_DIM + lane * 4);
    float s = v.x * v.x + v.y * v.y + v.z * v.z + v.w * v.w;
    #pragma unroll
    for (int off = 32; off; off >>= 1) s += __shfl_xor(s, off, 64);
    if (lane == 0) enorm[k] = s;
}

// ---------------------------------------------------------------- kernel 0b
// Eb[frag] = bf16(-2*E) laid out in MFMA B-fragment order:
// frag g = t*512 + kk*64 + l  holds E[code = t*16 + (l&15)][d = kk*32 + (l>>4)*8 .. +8]
__global__ __launch_bounds__(256) void vq_convert(const float* __restrict__ E,
                                                  short* __restrict__ Eb) {
    int g = blockIdx.x * 256 + threadIdx.x;      // 128 blocks -> [0, 32768)
    int t = g >> 9;
    int kk = (g >> 6) & 7;
    int l = g & 63;
    int code = t * 16 + (l & 15);
    int d = kk * 32 + ((l >> 4) << 3);
    const float* src = E + (size_t)code * D_DIM + d;
    float4 v0 = *reinterpret_cast<const float4*>(src);
    float4 v1 = *reinterpret_cast<const float4*>(src + 4);
    v0.x *= -2.f; v0.y *= -2.f; v0.z *= -2.f; v0.w *= -2.f;
    v1.x *= -2.f; v1.y *= -2.f; v1.z *= -2.f; v1.w *= -2.f;
    bf16x8 r = pack8(v0, v1);
    *reinterpret_cast<bf16x8*>(Eb + (size_t)g * 8) = r;
}

// ---------------------------------------------------------------- kernel 1
// Block = 32 rows; 4 waves K-split (wave w -> codes [w*256, w*256+256)).
// X rows live in registers as bf16 A-frags; scores via mfma (acc seeded with
// enorm, B = -2E). Register argmin -> cross-lane reduce -> LDS merge ->
// fused gather-writeback + loss partial.
__global__ __launch_bounds__(256, 3) void vq_main(const float* __restrict__ X,
                                                  const float* __restrict__ E,
                                                  const float* __restrict__ enorm,
                                                  const short* __restrict__ Eb,
                                                  float* __restrict__ outq,
                                                  float* __restrict__ loss_partial) {
    __shared__ float mv[4][BLOCK_ROWS];
    __shared__ int   mi[4][BLOCK_ROWS];
    __shared__ int   fidx[BLOCK_ROWS];
    __shared__ float wsum[4];

    const int tid  = threadIdx.x;
    const int wave = tid >> 6;
    const int l    = tid & 63;
    const int lr   = l & 15;      // row-in-16 (A) / code col (B,C)
    const int lk   = l >> 4;      // k-group
    const int brow0 = blockIdx.x * BLOCK_ROWS;

    // ---- prologue: 32 rows of X -> bf16 A-fragments (all 4 waves: same rows)
    bf16x8 a0[8], a1[8];
    {
        const float* x0 = X + (size_t)(brow0 + lr) * D_DIM + lk * 8;
        const float* x1 = X + (size_t)(brow0 + 16 + lr) * D_DIM + lk * 8;
        #pragma unroll
        for (int kk = 0; kk < 8; ++kk) {
            float4 p = *reinterpret_cast<const float4*>(x0 + kk * 32);
            float4 q = *reinterpret_cast<const float4*>(x0 + kk * 32 + 4);
            a0[kk] = pack8(p, q);
            float4 r = *reinterpret_cast<const float4*>(x1 + kk * 32);
            float4 s = *reinterpret_cast<const float4*>(x1 + kk * 32 + 4);
            a1[kk] = pack8(r, s);
        }
    }

    float minv0[4], minv1[4];
    int   mini0[4], mini1[4];
    #pragma unroll
    for (int i = 0; i < 4; ++i) {
        minv0[i] = INFINITY; mini0[i] = 0;
        minv1[i] = INFINITY; mini1[i] = 0;
    }

    // ---- main loop: 16 code-tiles of 16 codes for this wave
    const bf16x8* Ebf = (const bf16x8*)Eb;
    for (int tt = 0; tt < 16; ++tt) {
        const int t = wave * 16 + tt;

        bf16x8 braw[8];
        #pragma unroll
        for (int kk = 0; kk < 8; ++kk)
            braw[kk] = Ebf[(size_t)t * 512 + kk * 64 + l];

        const float en = enorm[t * 16 + lr];
        f32x4 acc0 = {en, en, en, en};
        f32x4 acc1 = {en, en, en, en};
        #pragma unroll
        for (int kk = 0; kk < 8; ++kk) {
            acc0 = __builtin_amdgcn_mfma_f32_16x16x32_bf16(a0[kk], braw[kk], acc0, 0, 0, 0);
            acc1 = __builtin_amdgcn_mfma_f32_16x16x32_bf16(a1[kk], braw[kk], acc1, 0, 0, 0);
        }

        const int idx = t * 16 + lr;
        #pragma unroll
        for (int i = 0; i < 4; ++i) {
            if (acc0[i] < minv0[i]) { minv0[i] = acc0[i]; mini0[i] = idx; }
            if (acc1[i] < minv1[i]) { minv1[i] = acc1[i]; mini1[i] = idx; }
        }
    }

    // ---- reduce over the 16 code-lanes of each group (first-min tie-break)
    #pragma unroll
    for (int off = 8; off >= 1; off >>= 1) {
        #pragma unroll
        for (int i = 0; i < 4; ++i) {
            float ov = __shfl_xor(minv0[i], off, 64);
            int   oi = __shfl_xor(mini0[i], off, 64);
            if (ov < minv0[i] || (ov == minv0[i] && oi < mini0[i])) { minv0[i] = ov; mini0[i] = oi; }
            ov = __shfl_xor(minv1[i], off, 64);
            oi = __shfl_xor(mini1[i], off, 64);
            if (ov < minv1[i] || (ov == minv1[i] && oi < mini1[i])) { minv1[i] = ov; mini1[i] = oi; }
        }
    }

    // ---- publish per-wave results, merge the 4 K-split waves
    if (lr == 0) {
        #pragma unroll
        for (int i = 0; i < 4; ++i) {
            mv[wave][lk * 4 + i]      = minv0[i];  mi[wave][lk * 4 + i]      = mini0[i];
            mv[wave][16 + lk * 4 + i] = minv1[i];  mi[wave][16 + lk * 4 + i] = mini1[i];
        }
    }
    __syncthreads();
    if (tid < BLOCK_ROWS) {
        float bv = mv[0][tid]; int bi = mi[0][tid];
        #pragma unroll
        for (int w = 1; w < 4; ++w) {
            float v = mv[w][tid]; int ii = mi[w][tid];
            if (v < bv || (v == bv && ii < bi)) { bv = v; bi = ii; }
        }
        fidx[tid] = bi;
    }
    __syncthreads();

    // ---- fused gather-writeback + loss (8 threads per row)
    float lsum = 0.0f;
    {
        const int r   = tid >> 3;       // 0..31
        const int c8  = tid & 7;
        const int row = brow0 + r;
        const int idx = fidx[r];
        const float* eq  = E + (size_t)idx * D_DIM;
        const float* xr  = X + (size_t)row * D_DIM;
        float*       orw = outq + (size_t)row * D_DIM;
        #pragma unroll
        for (int j = 0; j < 8; ++j) {
            int d = c8 * 4 + j * 32;
            float4 q = *reinterpret_cast<const float4*>(eq + d);
            float4 x = *reinterpret_cast<const float4*>(xr + d);
            *reinterpret_cast<float4*>(orw + d) = q;
            float dx = q.x - x.x, dy = q.y - x.y, dz = q.z - x.z, dw = q.w - x.w;
            lsum += dx * dx + dy * dy + dz * dz + dw * dw;
        }
    }
    #pragma unroll
    for (int off = 32; off; off >>= 1) lsum += __shfl_xor(lsum, off, 64);
    if (l == 0) wsum[wave] = lsum;
    __syncthreads();
    if (tid == 0)
        loss_partial[blockIdx.x] = wsum[0] + wsum[1] + wsum[2] + wsum[3];
}

// ---------------------------------------------------------------- kernel 2
// deterministic fold of 1024 block partials -> vq_loss scalar
__global__ __launch_bounds__(256) void vq_finalize(const float* __restrict__ partials,
                                                   float* __restrict__ out_loss) {
    __shared__ float s[256];
    int t = threadIdx.x;
    s[t] = partials[t] + partials[t + 256] + partials[t + 512] + partials[t + 768];
    __syncthreads();
    #pragma unroll
    for (int off = 128; off; off >>= 1) {
        if (t < off) s[t] += s[t + off];
        __syncthreads();
    }
    if (t == 0)
        out_loss[0] = s[0] * (1.25f / (float)((size_t)N_ROWS * D_DIM));
}

// ---------------------------------------------------------------- launch
extern "C" void kernel_launch(void* const* d_in, const int* in_sizes, int n_in,
                              void* d_out, int out_size, void* d_ws, size_t ws_size,
                              hipStream_t stream) {
    const float* X = (const float*)d_in[0];   // latents  [32768, 256] f32
    const float* E = (const float*)d_in[1];   // codebook [1024, 256]  f32
    float* out = (float*)d_out;               // 8388608 quantized + 1 loss

    float* enorm    = (float*)d_ws;                       // 1024 f32
    float* partials = enorm + K_CODES;                    // 1024 f32
    short* Eb       = (short*)(partials + NBLK);          // 512 KB bf16, 16B-aligned

    vq_enorm  <<<K_CODES / 4, 256, 0, stream>>>(E, enorm);
    vq_convert<<<128,         256, 0, stream>>>(E, Eb);
    vq_main   <<<NBLK,        256, 0, stream>>>(X, E, enorm, Eb, out, partials);
    vq_finalize<<<1,          256, 0, stream>>>(partials, out + (size_t)N_ROWS * D_DIM);
}

// Round 3
// 59.806 us; speedup vs baseline: 5.3014x; 1.0009x over previous
//
#include <hip/hip_runtime.h>
#include <hip/hip_bf16.h>

#define D_DIM 256
#define K_CODES 1024
#define N_ROWS (32 * 1024)
#define BLOCK_ROWS 64                 // rows per block (4 MFMA row-sets)
#define NBLK (N_ROWS / BLOCK_ROWS)    // 512 main blocks

typedef __attribute__((ext_vector_type(8))) short bf16x8;
typedef __attribute__((ext_vector_type(4))) float f32x4;

static __device__ __forceinline__ short f2bf(float f) {
    __hip_bfloat16 h = __float2bfloat16(f);   // RNE
    return *reinterpret_cast<short*>(&h);
}

static __device__ __forceinline__ bf16x8 pack8(float4 a, float4 b) {
    bf16x8 r;
    r[0] = f2bf(a.x); r[1] = f2bf(a.y); r[2] = f2bf(a.z); r[3] = f2bf(a.w);
    r[4] = f2bf(b.x); r[5] = f2bf(b.y); r[6] = f2bf(b.z); r[7] = f2bf(b.w);
    return r;
}

// ---------------------------------------------------------------- prep
// Fused: (a) enorm[k] = ||E[k]||^2  (one wave per code row, 256 blocks x 4)
//        (b) Eb = bf16(-2*E) in MFMA B-fragment order (blocks 0..127)
// frag g = t*512 + kk*64 + l  holds E[code = t*16 + (l&15)][d = kk*32 + (l>>4)*8 .. +8]
__global__ __launch_bounds__(256) void vq_prep(const float* __restrict__ E,
                                               float* __restrict__ enorm,
                                               short* __restrict__ Eb) {
    int wave = threadIdx.x >> 6;
    int lane = threadIdx.x & 63;
    int k = blockIdx.x * 4 + wave;               // [0,1024)
    const float4 v = *reinterpret_cast<const float4*>(E + k * D_DIM + lane * 4);
    float s = v.x * v.x + v.y * v.y + v.z * v.z + v.w * v.w;
    #pragma unroll
    for (int off = 32; off; off >>= 1) s += __shfl_xor(s, off, 64);
    if (lane == 0) enorm[k] = s;

    if (blockIdx.x < 128) {
        int g = blockIdx.x * 256 + threadIdx.x;  // [0, 32768)
        int t = g >> 9;
        int kk = (g >> 6) & 7;
        int l = g & 63;
        int code = t * 16 + (l & 15);
        int d = kk * 32 + ((l >> 4) << 3);
        const float* src = E + (size_t)code * D_DIM + d;
        float4 v0 = *reinterpret_cast<const float4*>(src);
        float4 v1 = *reinterpret_cast<const float4*>(src + 4);
        v0.x *= -2.f; v0.y *= -2.f; v0.z *= -2.f; v0.w *= -2.f;
        v1.x *= -2.f; v1.y *= -2.f; v1.z *= -2.f; v1.w *= -2.f;
        *reinterpret_cast<bf16x8*>(Eb + (size_t)g * 8) = pack8(v0, v1);
    }
}

// ---------------------------------------------------------------- main
// Block = 64 rows; 4 waves K-split (wave w -> codes [w*256, w*256+256)).
// X rows in registers as 4 bf16 A-frag sets; B fragments ping-pong
// prefetched; acc seeded with enorm (B = -2E) so acc = score directly.
__global__ __launch_bounds__(256, 2) void vq_main(const float* __restrict__ X,
                                                  const float* __restrict__ E,
                                                  const float* __restrict__ enorm,
                                                  const short* __restrict__ Eb,
                                                  float* __restrict__ outq,
                                                  float* __restrict__ loss_partial) {
    __shared__ float mv[4][BLOCK_ROWS];
    __shared__ int   mi[4][BLOCK_ROWS];
    __shared__ int   fidx[BLOCK_ROWS];
    __shared__ float wsum[4];

    const int tid  = threadIdx.x;
    const int wave = tid >> 6;
    const int l    = tid & 63;
    const int lr   = l & 15;      // row-in-16 (A) / code col (B,C)
    const int lk   = l >> 4;      // k-group
    const int brow0 = blockIdx.x * BLOCK_ROWS;

    // ---- prologue: 64 rows of X -> bf16 A-fragments (same for all waves)
    bf16x8 a[4][8];
    #pragma unroll
    for (int s = 0; s < 4; ++s) {
        const float* xp = X + (size_t)(brow0 + s * 16 + lr) * D_DIM + lk * 8;
        #pragma unroll
        for (int kk = 0; kk < 8; ++kk) {
            float4 p = *reinterpret_cast<const float4*>(xp + kk * 32);
            float4 q = *reinterpret_cast<const float4*>(xp + kk * 32 + 4);
            a[s][kk] = pack8(p, q);
        }
    }

    float minv[4][4];
    int   mini[4][4];
    #pragma unroll
    for (int s = 0; s < 4; ++s)
        #pragma unroll
        for (int i = 0; i < 4; ++i) { minv[s][i] = INFINITY; mini[s][i] = 0; }

    const bf16x8* Ebf = (const bf16x8*)Eb;
    bf16x8 b0[8], b1[8];
    {
        const int t = wave * 16;
        #pragma unroll
        for (int kk = 0; kk < 8; ++kk)
            b0[kk] = Ebf[(size_t)t * 512 + kk * 64 + l];
    }

#define COMPUTE(B, T)                                                         \
    do {                                                                      \
        const int t_ = (T);                                                   \
        const float en_ = enorm[t_ * 16 + lr];                                \
        f32x4 acc[4];                                                         \
        _Pragma("unroll")                                                     \
        for (int s = 0; s < 4; ++s) acc[s] = (f32x4){en_, en_, en_, en_};     \
        _Pragma("unroll")                                                     \
        for (int kk = 0; kk < 8; ++kk) {                                      \
            _Pragma("unroll")                                                 \
            for (int s = 0; s < 4; ++s)                                       \
                acc[s] = __builtin_amdgcn_mfma_f32_16x16x32_bf16(             \
                    a[s][kk], B[kk], acc[s], 0, 0, 0);                        \
        }                                                                     \
        const int idx_ = t_ * 16 + lr;                                        \
        _Pragma("unroll")                                                     \
        for (int s = 0; s < 4; ++s)                                           \
            _Pragma("unroll")                                                 \
            for (int i = 0; i < 4; ++i)                                       \
                if (acc[s][i] < minv[s][i]) {                                 \
                    minv[s][i] = acc[s][i]; mini[s][i] = idx_;                \
                }                                                             \
    } while (0)

    for (int tt = 0; tt < 16; tt += 2) {
        const int t = wave * 16 + tt;
        #pragma unroll
        for (int kk = 0; kk < 8; ++kk)
            b1[kk] = Ebf[(size_t)(t + 1) * 512 + kk * 64 + l];
        COMPUTE(b0, t);
        if (tt < 14) {
            #pragma unroll
            for (int kk = 0; kk < 8; ++kk)
                b0[kk] = Ebf[(size_t)(t + 2) * 512 + kk * 64 + l];
        }
        COMPUTE(b1, t + 1);
    }
#undef COMPUTE

    // ---- reduce over the 16 code-lanes (first-min tie-break)
    #pragma unroll
    for (int off = 8; off >= 1; off >>= 1) {
        #pragma unroll
        for (int s = 0; s < 4; ++s)
            #pragma unroll
            for (int i = 0; i < 4; ++i) {
                float ov = __shfl_xor(minv[s][i], off, 64);
                int   oi = __shfl_xor(mini[s][i], off, 64);
                if (ov < minv[s][i] || (ov == minv[s][i] && oi < mini[s][i])) {
                    minv[s][i] = ov; mini[s][i] = oi;
                }
            }
    }

    // ---- publish per-wave results, merge the 4 K-split waves
    if (lr == 0) {
        #pragma unroll
        for (int s = 0; s < 4; ++s)
            #pragma unroll
            for (int i = 0; i < 4; ++i) {
                mv[wave][s * 16 + lk * 4 + i] = minv[s][i];
                mi[wave][s * 16 + lk * 4 + i] = mini[s][i];
            }
    }
    __syncthreads();
    if (tid < BLOCK_ROWS) {
        float bv = mv[0][tid]; int bi = mi[0][tid];
        #pragma unroll
        for (int w = 1; w < 4; ++w) {
            float v = mv[w][tid]; int ii = mi[w][tid];
            if (v < bv || (v == bv && ii < bi)) { bv = v; bi = ii; }
        }
        fidx[tid] = bi;
    }
    __syncthreads();

    // ---- fused gather-writeback + loss (8 threads per row, 2 halves)
    float lsum = 0.0f;
    #pragma unroll
    for (int h = 0; h < 2; ++h) {
        const int r   = (tid >> 3) + h * 32;
        const int c8  = tid & 7;
        const int row = brow0 + r;
        const int idx = fidx[r];
        const float* eq  = E + (size_t)idx * D_DIM;
        const float* xr  = X + (size_t)row * D_DIM;
        float*       orw = outq + (size_t)row * D_DIM;
        #pragma unroll
        for (int j = 0; j < 8; ++j) {
            int d = c8 * 4 + j * 32;
            float4 q = *reinterpret_cast<const float4*>(eq + d);
            float4 x = *reinterpret_cast<const float4*>(xr + d);
            *reinterpret_cast<float4*>(orw + d) = q;
            float dx = q.x - x.x, dy = q.y - x.y, dz = q.z - x.z, dw = q.w - x.w;
            lsum += dx * dx + dy * dy + dz * dz + dw * dw;
        }
    }
    #pragma unroll
    for (int off = 32; off; off >>= 1) lsum += __shfl_xor(lsum, off, 64);
    if (l == 0) wsum[wave] = lsum;
    __syncthreads();
    if (tid == 0)
        loss_partial[blockIdx.x] = wsum[0] + wsum[1] + wsum[2] + wsum[3];
}

// ---------------------------------------------------------------- finalize
// deterministic fold of 512 block partials -> vq_loss scalar
__global__ __launch_bounds__(256) void vq_finalize(const float* __restrict__ partials,
                                                   float* __restrict__ out_loss) {
    __shared__ float s[256];
    int t = threadIdx.x;
    s[t] = partials[t] + partials[t + 256];
    __syncthreads();
    #pragma unroll
    for (int off = 128; off; off >>= 1) {
        if (t < off) s[t] += s[t + off];
        __syncthreads();
    }
    if (t == 0)
        out_loss[0] = s[0] * (1.25f / (float)((size_t)N_ROWS * D_DIM));
}

// ---------------------------------------------------------------- launch
extern "C" void kernel_launch(void* const* d_in, const int* in_sizes, int n_in,
                              void* d_out, int out_size, void* d_ws, size_t ws_size,
                              hipStream_t stream) {
    const float* X = (const float*)d_in[0];   // latents  [32768, 256] f32
    const float* E = (const float*)d_in[1];   // codebook [1024, 256]  f32
    float* out = (float*)d_out;               // 8388608 quantized + 1 loss

    float* enorm    = (float*)d_ws;                       // 1024 f32
    float* partials = enorm + K_CODES;                    // 1024 f32 slot (512 used)
    short* Eb       = (short*)(partials + 1024);          // 512 KB bf16, 16B-aligned

    vq_prep    <<<256,  256, 0, stream>>>(E, enorm, Eb);
    vq_main    <<<NBLK, 256, 0, stream>>>(X, E, enorm, Eb, out, partials);
    vq_finalize<<<1,    256, 0, stream>>>(partials, out + (size_t)N_ROWS * D_DIM);
}